// Round 1
// baseline (280.826 us; speedup 1.0000x reference)
//
#include <hip/hip_runtime.h>

// ---------------------------------------------------------------------------
// CavAttention: x(B,L,H,W,C) -> qkv -> per-(b,h,w) 5-token attention (8 heads,
// dim 32) -> out-proj -> (B,L,H,W,C).
// B=2 L=5 H=48 W=176 C=256, INNER=256, rows M_ALL = B*H*W*L = 84480.
// Pipeline: prep (weights->bf16, transposed [n][k]) ; qkv GEMM (bf16 MFMA) ;
// attention (wave shuffle) ; out GEMM (bf16 MFMA, fused bias + scatter).
// ---------------------------------------------------------------------------

typedef __attribute__((ext_vector_type(8))) short short8;
typedef __attribute__((ext_vector_type(4))) float f32x4;

#define M_ALL 84480
#define SCALE_F 0.17677669529663687f

__device__ __forceinline__ float b2f(unsigned short u) {
    union { unsigned u; float f; } x; x.u = ((unsigned)u) << 16; return x.f;
}
__device__ __forceinline__ unsigned short f2b(float f) {
    union { float f; unsigned u; } x; x.f = f;
    unsigned u = x.u;
    return (unsigned short)((u + 0x7FFFu + ((u >> 16) & 1u)) >> 16);
}

// decompose row r=(b,h,w,l) -> flat offset in (B,L,H,W,*) order (x and out)
__device__ __forceinline__ size_t row_to_xoff(int r) {
    int l = r % 5; int t = r / 5;
    int w = t % 176; t /= 176;
    int h = t % 48; int b = t / 48;
    return (size_t)(((b * 5 + l) * 48 + h) * 176 + w) * 256;
}

// --------------------------- prep: weights -> bf16, transposed [n][k] ------
__global__ __launch_bounds__(256) void k_prep(const float* __restrict__ wq,
                                              const float* __restrict__ wo,
                                              unsigned short* __restrict__ wqt,
                                              unsigned short* __restrict__ wot) {
    int i = blockIdx.x * 256 + threadIdx.x;      // grid covers 196608
    if (i < 196608) { int k = i / 768, n = i % 768; wqt[n * 256 + k] = f2b(wq[i]); }
    if (i < 65536)  { int k = i / 256, n = i % 256; wot[n * 256 + k] = f2b(wo[i]); }
}

// --------------------------- GEMM 1: qkv = Xp @ Wqkv -----------------------
// block: 64 rows (M), loop 12 N-chunks of 64, K=256 staged as 2 halves of 128
__global__ __launch_bounds__(256) void k_qkv(const float* __restrict__ x,
                                             const unsigned short* __restrict__ wqt, // [768][256]
                                             unsigned short* __restrict__ qkv) {     // [84480][768]
    __shared__ unsigned short As[64 * 264];   // [m][k], pad 256->264 (free 2-way banks)
    __shared__ unsigned short Bs[64 * 136];   // [n][k-half], pad 128->136
    const int tid = threadIdx.x;
    const int m0 = blockIdx.x * 64;

    // stage A: 64 rows x 256 k, fp32 -> bf16, gather rows by (b,h,w,l)
#pragma unroll
    for (int rep = 0; rep < 16; ++rep) {
        int e = rep * 1024 + tid * 4;
        int row = e >> 8, k = e & 255;
        size_t xo = row_to_xoff(m0 + row) + k;
        float4 v = *(const float4*)(x + xo);
        ushort4 o; o.x = f2b(v.x); o.y = f2b(v.y); o.z = f2b(v.z); o.w = f2b(v.w);
        *(ushort4*)&As[row * 264 + k] = o;
    }

    const int wv = tid >> 6, lane = tid & 63;
    const int ln = lane & 15, quad = lane >> 4;
    const int m_w = (wv >> 1) * 32, n_w = (wv & 1) * 32;

    for (int nc = 0; nc < 12; ++nc) {
        const int n0 = nc * 64;
        f32x4 acc[2][2];
#pragma unroll
        for (int i = 0; i < 2; ++i)
#pragma unroll
            for (int j = 0; j < 2; ++j) acc[i][j] = (f32x4){0.f, 0.f, 0.f, 0.f};

        for (int kh = 0; kh < 2; ++kh) {
            __syncthreads();   // protect Bs from previous iteration's readers
#pragma unroll
            for (int rep = 0; rep < 4; ++rep) {
                int flat = rep * 2048 + tid * 8;
                int nl = flat >> 7;        // 0..63
                int kl = flat & 127;       // multiple of 8
                const unsigned short* src = wqt + (size_t)(n0 + nl) * 256 + kh * 128 + kl;
                ushort4 p0 = *(const ushort4*)(src);
                ushort4 p1 = *(const ushort4*)(src + 4);
                *(ushort4*)&Bs[nl * 136 + kl] = p0;
                *(ushort4*)&Bs[nl * 136 + kl + 4] = p1;
            }
            __syncthreads();
#pragma unroll
            for (int kk = 0; kk < 4; ++kk) {
                int ka = kh * 128 + kk * 32 + quad * 8;
                int kb = kk * 32 + quad * 8;
                short8 a0 = *(const short8*)&As[(m_w + ln) * 264 + ka];
                short8 a1 = *(const short8*)&As[(m_w + 16 + ln) * 264 + ka];
                short8 b0 = *(const short8*)&Bs[(n_w + ln) * 136 + kb];
                short8 b1 = *(const short8*)&Bs[(n_w + 16 + ln) * 136 + kb];
                acc[0][0] = __builtin_amdgcn_mfma_f32_16x16x32_bf16(a0, b0, acc[0][0], 0, 0, 0);
                acc[0][1] = __builtin_amdgcn_mfma_f32_16x16x32_bf16(a0, b1, acc[0][1], 0, 0, 0);
                acc[1][0] = __builtin_amdgcn_mfma_f32_16x16x32_bf16(a1, b0, acc[1][0], 0, 0, 0);
                acc[1][1] = __builtin_amdgcn_mfma_f32_16x16x32_bf16(a1, b1, acc[1][1], 0, 0, 0);
            }
        }
        // C/D layout: col = lane&15, row = quad*4 + reg  (m89/m91-verified)
#pragma unroll
        for (int i = 0; i < 2; ++i)
#pragma unroll
            for (int j = 0; j < 2; ++j) {
                int row = m0 + m_w + 16 * i + quad * 4;
                int col = n0 + n_w + 16 * j + ln;
#pragma unroll
                for (int rg = 0; rg < 4; ++rg)
                    qkv[(size_t)(row + rg) * 768 + col] = f2b(acc[i][j][rg]);
            }
    }
}

// --------------------------- attention -------------------------------------
// block = 64 threads = 8 heads x 8 lanes, each lane owns 4 dims.
__global__ __launch_bounds__(64) void k_attn(const unsigned short* __restrict__ qkv,
                                             const int* __restrict__ mask,
                                             unsigned short* __restrict__ att) {
    const int p = blockIdx.x;            // (b,h,w) flat, 0..16895
    const int g = threadIdx.x >> 3;      // head 0..7
    const int l8 = threadIdx.x & 7;      // dim quad
    const size_t base = (size_t)p * 3840 + g * 32 + l8 * 4;

    float q[5][4], k[5][4], v[5][4];
#pragma unroll
    for (int i = 0; i < 5; ++i) {
        ushort4 uq = *(const ushort4*)(qkv + base + i * 768);
        ushort4 uk = *(const ushort4*)(qkv + base + i * 768 + 256);
        ushort4 uv = *(const ushort4*)(qkv + base + i * 768 + 512);
        q[i][0] = b2f(uq.x); q[i][1] = b2f(uq.y); q[i][2] = b2f(uq.z); q[i][3] = b2f(uq.w);
        k[i][0] = b2f(uk.x); k[i][1] = b2f(uk.y); k[i][2] = b2f(uk.z); k[i][3] = b2f(uk.w);
        v[i][0] = b2f(uv.x); v[i][1] = b2f(uv.y); v[i][2] = b2f(uv.z); v[i][3] = b2f(uv.w);
    }

    float s[5][5];
#pragma unroll
    for (int i = 0; i < 5; ++i)
#pragma unroll
        for (int j = 0; j < 5; ++j)
            s[i][j] = q[i][0] * k[j][0] + q[i][1] * k[j][1] + q[i][2] * k[j][2] + q[i][3] * k[j][3];
    // reduce over the 8 lanes of this head
#pragma unroll
    for (int off = 4; off >= 1; off >>= 1)
#pragma unroll
        for (int i = 0; i < 5; ++i)
#pragma unroll
            for (int j = 0; j < 5; ++j) s[i][j] += __shfl_xor(s[i][j], off, 64);

    int mk[5];
#pragma unroll
    for (int j = 0; j < 5; ++j) mk[j] = mask[p * 5 + j];

    float pr[5][5];
#pragma unroll
    for (int i = 0; i < 5; ++i) {
        float mx = -1e30f;
#pragma unroll
        for (int j = 0; j < 5; ++j) {
            s[i][j] = mk[j] ? s[i][j] * SCALE_F : -1e30f;
            mx = fmaxf(mx, s[i][j]);
        }
        float sum = 0.f;
#pragma unroll
        for (int j = 0; j < 5; ++j) { pr[i][j] = __expf(s[i][j] - mx); sum += pr[i][j]; }
        float inv = 1.f / sum;
#pragma unroll
        for (int j = 0; j < 5; ++j) pr[i][j] *= inv;
    }

#pragma unroll
    for (int i = 0; i < 5; ++i) {
        float o0 = 0.f, o1 = 0.f, o2 = 0.f, o3 = 0.f;
#pragma unroll
        for (int j = 0; j < 5; ++j) {
            o0 += pr[i][j] * v[j][0]; o1 += pr[i][j] * v[j][1];
            o2 += pr[i][j] * v[j][2]; o3 += pr[i][j] * v[j][3];
        }
        ushort4 u; u.x = f2b(o0); u.y = f2b(o1); u.z = f2b(o2); u.w = f2b(o3);
        *(ushort4*)(att + (size_t)(p * 5 + i) * 256 + g * 32 + l8 * 4) = u;
    }
}

// --------------------------- GEMM 2: out = Att @ Wout + b ------------------
__global__ __launch_bounds__(256) void k_out(const unsigned short* __restrict__ att, // [84480][256]
                                             const unsigned short* __restrict__ wot, // [256][256] ([n][k])
                                             const float* __restrict__ bo,
                                             float* __restrict__ out) {
    __shared__ unsigned short As[64 * 264];
    __shared__ unsigned short Bs[64 * 136];
    const int tid = threadIdx.x;
    const int m0 = blockIdx.x * 64;

#pragma unroll
    for (int rep = 0; rep < 8; ++rep) {
        int flat = rep * 2048 + tid * 8;
        int row = flat >> 8;          // 0..63
        int k = flat & 255;           // multiple of 8
        const unsigned short* src = att + (size_t)(m0 + row) * 256 + k;
        ushort4 p0 = *(const ushort4*)(src);
        ushort4 p1 = *(const ushort4*)(src + 4);
        *(ushort4*)&As[row * 264 + k] = p0;
        *(ushort4*)&As[row * 264 + k + 4] = p1;
    }

    const int wv = tid >> 6, lane = tid & 63;
    const int ln = lane & 15, quad = lane >> 4;
    const int m_w = (wv >> 1) * 32, n_w = (wv & 1) * 32;

    for (int nc = 0; nc < 4; ++nc) {
        const int n0 = nc * 64;
        f32x4 acc[2][2];
#pragma unroll
        for (int i = 0; i < 2; ++i)
#pragma unroll
            for (int j = 0; j < 2; ++j) acc[i][j] = (f32x4){0.f, 0.f, 0.f, 0.f};

        for (int kh = 0; kh < 2; ++kh) {
            __syncthreads();
#pragma unroll
            for (int rep = 0; rep < 4; ++rep) {
                int flat = rep * 2048 + tid * 8;
                int nl = flat >> 7;
                int kl = flat & 127;
                const unsigned short* src = wot + (size_t)(n0 + nl) * 256 + kh * 128 + kl;
                ushort4 p0 = *(const ushort4*)(src);
                ushort4 p1 = *(const ushort4*)(src + 4);
                *(ushort4*)&Bs[nl * 136 + kl] = p0;
                *(ushort4*)&Bs[nl * 136 + kl + 4] = p1;
            }
            __syncthreads();
#pragma unroll
            for (int kk = 0; kk < 4; ++kk) {
                int ka = kh * 128 + kk * 32 + quad * 8;
                int kb = kk * 32 + quad * 8;
                short8 a0 = *(const short8*)&As[(m_w + ln) * 264 + ka];
                short8 a1 = *(const short8*)&As[(m_w + 16 + ln) * 264 + ka];
                short8 b0 = *(const short8*)&Bs[(n_w + ln) * 136 + kb];
                short8 b1 = *(const short8*)&Bs[(n_w + 16 + ln) * 136 + kb];
                acc[0][0] = __builtin_amdgcn_mfma_f32_16x16x32_bf16(a0, b0, acc[0][0], 0, 0, 0);
                acc[0][1] = __builtin_amdgcn_mfma_f32_16x16x32_bf16(a0, b1, acc[0][1], 0, 0, 0);
                acc[1][0] = __builtin_amdgcn_mfma_f32_16x16x32_bf16(a1, b0, acc[1][0], 0, 0, 0);
                acc[1][1] = __builtin_amdgcn_mfma_f32_16x16x32_bf16(a1, b1, acc[1][1], 0, 0, 0);
            }
        }
        float bv0 = bo[n0 + n_w + ln];
        float bv1 = bo[n0 + n_w + 16 + ln];
#pragma unroll
        for (int i = 0; i < 2; ++i)
#pragma unroll
            for (int rg = 0; rg < 4; ++rg) {
                int r = m0 + m_w + 16 * i + quad * 4 + rg;
                size_t off = row_to_xoff(r);
                out[off + n0 + n_w + ln] = acc[i][0][rg] + bv0;
                out[off + n0 + n_w + 16 + ln] = acc[i][1][rg] + bv1;
            }
    }
}

// ---------------------------------------------------------------------------
extern "C" void kernel_launch(void* const* d_in, const int* in_sizes, int n_in,
                              void* d_out, int out_size, void* d_ws, size_t ws_size,
                              hipStream_t stream) {
    const float* x   = (const float*)d_in[0];
    const int* mask  = (const int*)d_in[1];
    const float* wq  = (const float*)d_in[2];
    const float* wo  = (const float*)d_in[3];
    const float* bo  = (const float*)d_in[4];
    float* out = (float*)d_out;

    char* ws = (char*)d_ws;
    // ws layout (bytes): qkv bf16 [84480][768] | att bf16 [84480][256] | wqt | wot
    unsigned short* qkv = (unsigned short*)(ws);
    unsigned short* att = (unsigned short*)(ws + 129761280);
    unsigned short* wqt = (unsigned short*)(ws + 173015040);
    unsigned short* wot = (unsigned short*)(ws + 173408256);
    // total ws use: 173,539,328 bytes

    hipLaunchKernelGGL(k_prep, dim3(768), dim3(256), 0, stream, wq, wo, wqt, wot);
    hipLaunchKernelGGL(k_qkv, dim3(1320), dim3(256), 0, stream, x, wqt, qkv);
    hipLaunchKernelGGL(k_attn, dim3(16896), dim3(64), 0, stream, qkv, mask, att);
    hipLaunchKernelGGL(k_out, dim3(1320), dim3(256), 0, stream, att, wot, bo, out);
}